// Round 7
// baseline (205.614 us; speedup 1.0000x reference)
//
#include <hip/hip_runtime.h>
#include <math.h>

#define B 2
#define C 32
#define H 128
#define W 416
#define D 48
#define HW (H*W)
#define CHW (C*HW)
#define EPSN 1e-3f
#define ISCALE 0.05892556509887896f   // 1/sqrt(C*9)
#define LSTRH 40                       // LDS column stride in halves: 80B -> 16B-aligned cols
#define NDSP 4                         // d-split factor
#define DSPL (D / NDSP)                // 12 disparities per block
#define HC 4                           // h-chunks in k_lr2
#define HB (H / HC)                    // 32 rows per chunk

typedef _Float16 half2v __attribute__((ext_vector_type(2)));
typedef _Float16 half4v __attribute__((ext_vector_type(4)));
typedef _Float16 half8v __attribute__((ext_vector_type(8)));

#if defined(__has_builtin)
#if __has_builtin(__builtin_amdgcn_fdot2)
#define FDOT2(a, b, c) __builtin_amdgcn_fdot2((a), (b), (c), false)
#endif
#endif
#ifndef FDOT2
#define FDOT2(a, b, c) ((c) + (float)(a)[0] * (float)(b)[0] + (float)(a)[1] * (float)(b)[1])
#endif

__device__ __forceinline__ float clip10(float x) {
    return fminf(fmaxf(x, -10.0f), 10.0f);
}

// ---------------------------------------------------------------------------
// k_sq: per-pixel sum over channels of squares for xl/xr; inverse norm for xm.
__global__ __launch_bounds__(256) void k_sq(const float* __restrict__ xl,
                                            const float* __restrict__ xr,
                                            const float* __restrict__ xm,
                                            float* __restrict__ sql,
                                            float* __restrict__ sqr,
                                            float* __restrict__ inm) {
    int idx = blockIdx.x * 256 + threadIdx.x;   // [0, B*HW)
    if (idx >= B * HW) return;
    int b = idx / HW, hw = idx - b * HW;
    const float* pl = xl + (size_t)b * CHW + hw;
    const float* pr = xr + (size_t)b * CHW + hw;
    const float* pm = xm + (size_t)b * CHW + hw;
    float al = 0.f, ar = 0.f, am = 0.f;
#pragma unroll
    for (int c = 0; c < C; ++c) {
        float vl = pl[c * HW], vr = pr[c * HW], vm = pm[c * HW];
        al += vl * vl; ar += vr * vr; am += vm * vm;
    }
    sql[idx] = al;
    sqr[idx] = ar;
    inm[idx] = 1.0f / fmaxf(sqrtf(am), EPSN);
}

// ---------------------------------------------------------------------------
// k_norm: 3x3 zero-padded box of sql/sqr -> inverse patch norms inl/inr.
__global__ __launch_bounds__(256) void k_norm(const float* __restrict__ sql,
                                              const float* __restrict__ sqr,
                                              float* __restrict__ inl,
                                              float* __restrict__ inr) {
    int idx = blockIdx.x * 256 + threadIdx.x;
    if (idx >= B * HW) return;
    int b = idx / HW, hw = idx - b * HW;
    int h = hw / W, w = hw - h * W;
    float sl = 0.f, sr = 0.f;
#pragma unroll
    for (int di = -1; di <= 1; ++di) {
        int hh = h + di;
        if (hh < 0 || hh >= H) continue;
#pragma unroll
        for (int dj = -1; dj <= 1; ++dj) {
            int ww = w + dj;
            if (ww < 0 || ww >= W) continue;
            int p = b * HW + hh * W + ww;
            sl += sql[p];
            sr += sqr[p];
        }
    }
    inl[idx] = 1.0f / fmaxf(sqrtf(sl), EPSN);
    inr[idx] = 1.0f / fmaxf(sqrtf(sr), EPSN);
}

// ---------------------------------------------------------------------------
// k_box: per-channel 3x3 zero-padded box sums, 4 outputs/thread, f16 output.
__global__ __launch_bounds__(256) void k_box(const float* __restrict__ xl,
                                             const float* __restrict__ xr,
                                             _Float16* __restrict__ boxl,
                                             _Float16* __restrict__ boxr) {
    int idx = blockIdx.x * 256 + threadIdx.x;   // [0, B*C*H*W/4)
    int w4 = (idx % (W / 4)) * 4;
    int h = (idx / (W / 4)) % H;
    int rest = idx / (H * (W / 4));             // b*C + c
    size_t base = (size_t)rest * HW;
    float4 al = {0.f, 0.f, 0.f, 0.f}, ar = {0.f, 0.f, 0.f, 0.f};
#pragma unroll
    for (int dh = -1; dh <= 1; ++dh) {
        int hh = h + dh;
        if (hh < 0 || hh >= H) continue;
        const float* rl = xl + base + hh * W;
        const float* rr = xr + base + hh * W;
        float4 m = *(const float4*)(rl + w4);
        float lm = (w4 > 0) ? rl[w4 - 1] : 0.f;
        float rm = (w4 + 4 < W) ? rl[w4 + 4] : 0.f;
        al.x += lm + m.x + m.y;  al.y += m.x + m.y + m.z;
        al.z += m.y + m.z + m.w; al.w += m.z + m.w + rm;
        float4 n = *(const float4*)(rr + w4);
        float ln = (w4 > 0) ? rr[w4 - 1] : 0.f;
        float rn = (w4 + 4 < W) ? rr[w4 + 4] : 0.f;
        ar.x += ln + n.x + n.y;  ar.y += n.x + n.y + n.z;
        ar.z += n.y + n.z + n.w; ar.w += n.z + n.w + rn;
    }
    half4v ol = {(_Float16)al.x, (_Float16)al.y, (_Float16)al.z, (_Float16)al.w};
    half4v orr = {(_Float16)ar.x, (_Float16)ar.y, (_Float16)ar.z, (_Float16)ar.w};
    *(half4v*)(boxl + base + h * W + w4) = ol;
    *(half4v*)(boxr + base + h * W + w4) = orr;
}

// ---------------------------------------------------------------------------
// stage_row_h: stage [C][W] f16 row into LDS transposed [w][c], stride LSTRH.
__device__ __forceinline__ void stage_row_h(const _Float16* __restrict__ gsrc,
                                            _Float16* __restrict__ lds,
                                            int tid, int nthreads) {
    for (int t = tid; t < (W / 4) * C; t += nthreads) {
        int rw = t & 7;
        int cl = (t >> 3) & 7;
        int g  = t >> 6;              // 0..51
        int wg = g % 13;
        int ch = g / 13;              // 0..3
        int c  = ch * 8 + cl;
        int w4 = (wg * 8 + rw) * 4;
        half4v v = *(const half4v*)(gsrc + (size_t)c * HW + w4);
        lds[(w4 + 0) * LSTRH + c] = v[0];
        lds[(w4 + 1) * LSTRH + c] = v[1];
        lds[(w4 + 2) * LSTRH + c] = v[2];
        lds[(w4 + 3) * LSTRH + c] = v[3];
    }
}

// same but f32 source with convert-on-stage
__device__ __forceinline__ void stage_row_cvt(const float* __restrict__ gsrc,
                                              _Float16* __restrict__ lds,
                                              int tid, int nthreads) {
    for (int t = tid; t < (W / 4) * C; t += nthreads) {
        int rw = t & 7;
        int cl = (t >> 3) & 7;
        int g  = t >> 6;
        int wg = g % 13;
        int ch = g / 13;
        int c  = ch * 8 + cl;
        int w4 = (wg * 8 + rw) * 4;
        float4 v = *(const float4*)(gsrc + (size_t)c * HW + w4);
        lds[(w4 + 0) * LSTRH + c] = (_Float16)v.x;
        lds[(w4 + 1) * LSTRH + c] = (_Float16)v.y;
        lds[(w4 + 2) * LSTRH + c] = (_Float16)v.z;
        lds[(w4 + 3) * LSTRH + c] = (_Float16)v.w;
    }
}

// dot over 32 channels: col is 16B-aligned LDS column (32 f16 = 4 b128)
__device__ __forceinline__ float dot16(const half2v* __restrict__ a,
                                       const _Float16* __restrict__ col) {
    const half8v* c8 = (const half8v*)col;
    float s = 0.f;
#pragma unroll
    for (int q = 0; q < 4; ++q) {
        half8v v = c8[q];
#pragma unroll
        for (int i = 0; i < 4; ++i) {
            half2v p = {v[2 * i], v[2 * i + 1]};
            s = FDOT2(a[4 * q + i], p, s);
        }
    }
    return s;
}

// ---------------------------------------------------------------------------
// k_elr: fused E/sL/sR. One block per (b,h,dc), 448 threads, three phases
// sharing one 33KB LDS tile (4 blocks/CU).
//  E phase : EH[b,d,h,v] = horiz 3-tap of sum_c xl[.,v+2d]*xr[.,v]  (f16 out)
//  L phase : sL(d)[w] = fl . boxl[w+d] * inl[w+d]
//  R phase : sR(d)[w] = fl . boxr[w-d] * inr[w-d]
__global__ __launch_bounds__(448) void k_elr(const float* __restrict__ xl,
                                             const float* __restrict__ xr,
                                             const float* __restrict__ xm,
                                             const _Float16* __restrict__ boxl,
                                             const _Float16* __restrict__ boxr,
                                             const float* __restrict__ inl,
                                             const float* __restrict__ inr,
                                             const float* __restrict__ inm,
                                             _Float16* __restrict__ EH,
                                             float* __restrict__ out) {
    __shared__ _Float16 sB[W * LSTRH];   // 33280 B
    __shared__ float sIn[W];
    int tid = threadIdx.x;
    int h = blockIdx.x;
    int b = blockIdx.y;
    int d0 = blockIdx.z * DSPL;
    int bhw = b * HW + h * W;

    // ---- E phase: wave-halo mapping ----
    {
        int lane = tid & 63;
        int wv = tid >> 6;                // 0..6
        int v = wv * 62 + lane - 1;       // -1 .. 433
        bool vin = (v >= 0) && (v < W);
        const float* br = xr + (size_t)b * CHW + h * W;

        half2v xrv[C / 2];
#pragma unroll
        for (int c2 = 0; c2 < C / 2; ++c2) {
            float va = vin ? br[(2 * c2) * HW + v] : 0.f;
            float vb = vin ? br[(2 * c2 + 1) * HW + v] : 0.f;
            half2v x = {(_Float16)va, (_Float16)vb};
            xrv[c2] = x;
        }

        stage_row_cvt(xl + (size_t)b * CHW + h * W, sB, tid, 448);
        __syncthreads();

        bool wr = (lane >= 1) && (lane <= 62) && (v < W);   // v>=0 implied
        _Float16* pe = EH + (((size_t)b * D) * H + h) * W + v;
        for (int d = d0; d < d0 + DSPL; ++d) {
            int s = 2 * d;
            float e = 0.0f;
            if (vin && v + s < W) e = dot16(xrv, sB + (v + s) * LSTRH);
            float em = __shfl_up(e, 1);
            float ep = __shfl_down(e, 1);
            float eh = em + e + ep;
            if (wr) pe[(size_t)d * HW] = (_Float16)eh;
        }
        __syncthreads();
    }

    // ---- load fl fragment (w = tid mapping) ----
    int w = tid;
    bool act = w < W;
    half2v fl[C / 2];
    {
        const float* pm = xm + (size_t)b * CHW + h * W;
        float im = act ? inm[bhw + w] : 0.f;
#pragma unroll
        for (int c2 = 0; c2 < C / 2; ++c2) {
            float va = act ? pm[(2 * c2) * HW + w] : 0.f;
            float vb = act ? pm[(2 * c2 + 1) * HW + w] : 0.f;
            half2v f = {(_Float16)(va * im), (_Float16)(vb * im)};
            fl[c2] = f;
        }
    }

    // ---- L phase ----
    stage_row_h(boxl + (size_t)b * CHW + h * W, sB, tid, 448);
    for (int j = tid; j < W; j += 448) sIn[j] = inl[bhw + j];
    __syncthreads();
    if (act) {
        float* o = out + ((size_t)b * 3 + 0) * D * HW + h * W + w;
        for (int d = d0; d < d0 + DSPL; ++d) {
            float oL = 0.f;
            int v = w + d;
            if (v < W) {
                float a = dot16(fl, sB + v * LSTRH);
                oL = clip10(a * sIn[v] * ISCALE);
            }
            o[(size_t)d * HW] = oL;
        }
    }
    __syncthreads();

    // ---- R phase ----
    stage_row_h(boxr + (size_t)b * CHW + h * W, sB, tid, 448);
    for (int j = tid; j < W; j += 448) sIn[j] = inr[bhw + j];
    __syncthreads();
    if (act) {
        float* o = out + ((size_t)b * 3 + 1) * D * HW + h * W + w;
        for (int d = d0; d < d0 + DSPL; ++d) {
            float oR = 0.f;
            int v = w - d;
            if (v >= 0) {
                float a = dot16(fl, sB + v * LSTRH);
                oR = clip10(a * sIn[v] * ISCALE);
            }
            o[(size_t)d * HW] = oR;
        }
    }
}

// ---------------------------------------------------------------------------
// k_lr2: sLR = vertical 3-tap of EH, rolling register window over h.
// Thread owns (w,d); each EH element is loaded exactly once.
__global__ __launch_bounds__(256) void k_lr2(const _Float16* __restrict__ EH,
                                             const float* __restrict__ inl,
                                             const float* __restrict__ inr,
                                             float* __restrict__ out) {
    int tid = threadIdx.x;
    int w = blockIdx.x * 256 + tid;    // grid.x = 2
    int d = blockIdx.y;                // 0..47
    int z = blockIdx.z;                // b*HC + hc
    int b = z / HC, hc = z - b * HC;
    if (w >= W) return;
    int vc = w - d;
    bool valid = (vc >= 0) && (w + d < W);
    int h0 = hc * HB;

    const _Float16* pe = EH + ((size_t)b * D + d) * HW + vc;
    const float* pl = inl + b * HW + w + d;
    const float* pr = inr + b * HW + vc;
    float* o = out + ((size_t)b * 3 + 2) * D * HW + (size_t)d * HW + w;

    float em = 0.f, e0 = 0.f;
    if (valid) {
        em = (h0 > 0) ? (float)pe[(h0 - 1) * W] : 0.f;
        e0 = (float)pe[h0 * W];
    }
#pragma unroll 4
    for (int h = h0; h < h0 + HB; ++h) {
        float r = 0.f;
        if (valid) {
            float ep = (h + 1 < H) ? (float)pe[(h + 1) * W] : 0.f;
            float e = em + e0 + ep;
            r = clip10(e * pl[h * W] * pr[h * W] * ISCALE);
            em = e0; e0 = ep;
        }
        o[h * W] = r;
    }
}

// ---------------------------------------------------------------------------
extern "C" void kernel_launch(void* const* d_in, const int* in_sizes, int n_in,
                              void* d_out, int out_size, void* d_ws, size_t ws_size,
                              hipStream_t stream) {
    const float* xl = (const float*)d_in[0];
    const float* xm = (const float*)d_in[1];
    const float* xr = (const float*)d_in[2];
    float* out = (float*)d_out;

    float* ws = (float*)d_ws;
    float* inl  = ws;                              // B*HW fp32
    float* inr  = inl + B * HW;
    float* inm  = inr + B * HW;
    float* sql  = inm + B * HW;
    float* sqr  = sql + B * HW;
    _Float16* boxl = (_Float16*)(sqr + B * HW);    // B*C*H*W f16
    _Float16* boxr = boxl + (size_t)B * CHW;
    _Float16* EH   = boxr + (size_t)B * CHW;       // B*D*H*W f16

    k_sq<<<dim3((B * HW + 255) / 256), dim3(256), 0, stream>>>(xl, xr, xm, sql, sqr, inm);
    k_norm<<<dim3((B * HW + 255) / 256), dim3(256), 0, stream>>>(sql, sqr, inl, inr);
    k_box<<<dim3((B * CHW / 4 + 255) / 256), dim3(256), 0, stream>>>(xl, xr, boxl, boxr);
    k_elr<<<dim3(H, B, NDSP), dim3(448), 0, stream>>>(xl, xr, xm, boxl, boxr,
                                                      inl, inr, inm, EH, out);
    k_lr2<<<dim3(2, D, B * HC), dim3(256), 0, stream>>>(EH, inl, inr, out);
}

// Round 8
// 200.827 us; speedup vs baseline: 1.0238x; 1.0238x over previous
//
#include <hip/hip_runtime.h>
#include <math.h>

#define B 2
#define C 32
#define H 128
#define W 416
#define D 48
#define HW (H*W)
#define CHW (C*HW)
#define EPSN 1e-3f
#define ISCALE 0.05892556509887896f   // 1/sqrt(C*9)
#define LSTRH 40                       // LDS column stride in halves: 80B -> 16B-aligned cols
#define NDSP 4                         // d-split factor
#define DSPL (D / NDSP)                // 12 disparities per block
#define HC 4                           // h-chunks in k_lr2
#define HB (H / HC)                    // 32 rows per chunk

typedef _Float16 half2v __attribute__((ext_vector_type(2)));
typedef _Float16 half4v __attribute__((ext_vector_type(4)));
typedef _Float16 half8v __attribute__((ext_vector_type(8)));

#if defined(__has_builtin)
#if __has_builtin(__builtin_amdgcn_fdot2)
#define FDOT2(a, b, c) __builtin_amdgcn_fdot2((a), (b), (c), false)
#endif
#endif
#ifndef FDOT2
#define FDOT2(a, b, c) ((c) + (float)(a)[0] * (float)(b)[0] + (float)(a)[1] * (float)(b)[1])
#endif

__device__ __forceinline__ float clip10(float x) {
    return fminf(fmaxf(x, -10.0f), 10.0f);
}

// ---------------------------------------------------------------------------
// k_sq: per-pixel sum over channels of squares for xl/xr; inverse norm for xm.
__global__ __launch_bounds__(256) void k_sq(const float* __restrict__ xl,
                                            const float* __restrict__ xr,
                                            const float* __restrict__ xm,
                                            float* __restrict__ sql,
                                            float* __restrict__ sqr,
                                            float* __restrict__ inm) {
    int idx = blockIdx.x * 256 + threadIdx.x;   // [0, B*HW)
    if (idx >= B * HW) return;
    int b = idx / HW, hw = idx - b * HW;
    const float* pl = xl + (size_t)b * CHW + hw;
    const float* pr = xr + (size_t)b * CHW + hw;
    const float* pm = xm + (size_t)b * CHW + hw;
    float al = 0.f, ar = 0.f, am = 0.f;
#pragma unroll
    for (int c = 0; c < C; ++c) {
        float vl = pl[c * HW], vr = pr[c * HW], vm = pm[c * HW];
        al += vl * vl; ar += vr * vr; am += vm * vm;
    }
    sql[idx] = al;
    sqr[idx] = ar;
    inm[idx] = 1.0f / fmaxf(sqrtf(am), EPSN);
}

// ---------------------------------------------------------------------------
// k_norm: 3x3 zero-padded box of sql/sqr -> inverse patch norms inl/inr.
__global__ __launch_bounds__(256) void k_norm(const float* __restrict__ sql,
                                              const float* __restrict__ sqr,
                                              float* __restrict__ inl,
                                              float* __restrict__ inr) {
    int idx = blockIdx.x * 256 + threadIdx.x;
    if (idx >= B * HW) return;
    int b = idx / HW, hw = idx - b * HW;
    int h = hw / W, w = hw - h * W;
    float sl = 0.f, sr = 0.f;
#pragma unroll
    for (int di = -1; di <= 1; ++di) {
        int hh = h + di;
        if (hh < 0 || hh >= H) continue;
#pragma unroll
        for (int dj = -1; dj <= 1; ++dj) {
            int ww = w + dj;
            if (ww < 0 || ww >= W) continue;
            int p = b * HW + hh * W + ww;
            sl += sql[p];
            sr += sqr[p];
        }
    }
    inl[idx] = 1.0f / fmaxf(sqrtf(sl), EPSN);
    inr[idx] = 1.0f / fmaxf(sqrtf(sr), EPSN);
}

// ---------------------------------------------------------------------------
// k_box: per-channel 3x3 zero-padded box sums, 4 outputs/thread, f16 output.
__global__ __launch_bounds__(256) void k_box(const float* __restrict__ xl,
                                             const float* __restrict__ xr,
                                             _Float16* __restrict__ boxl,
                                             _Float16* __restrict__ boxr) {
    int idx = blockIdx.x * 256 + threadIdx.x;   // [0, B*C*H*W/4)
    int w4 = (idx % (W / 4)) * 4;
    int h = (idx / (W / 4)) % H;
    int rest = idx / (H * (W / 4));             // b*C + c
    size_t base = (size_t)rest * HW;
    float4 al = {0.f, 0.f, 0.f, 0.f}, ar = {0.f, 0.f, 0.f, 0.f};
#pragma unroll
    for (int dh = -1; dh <= 1; ++dh) {
        int hh = h + dh;
        if (hh < 0 || hh >= H) continue;
        const float* rl = xl + base + hh * W;
        const float* rr = xr + base + hh * W;
        float4 m = *(const float4*)(rl + w4);
        float lm = (w4 > 0) ? rl[w4 - 1] : 0.f;
        float rm = (w4 + 4 < W) ? rl[w4 + 4] : 0.f;
        al.x += lm + m.x + m.y;  al.y += m.x + m.y + m.z;
        al.z += m.y + m.z + m.w; al.w += m.z + m.w + rm;
        float4 n = *(const float4*)(rr + w4);
        float ln = (w4 > 0) ? rr[w4 - 1] : 0.f;
        float rn = (w4 + 4 < W) ? rr[w4 + 4] : 0.f;
        ar.x += ln + n.x + n.y;  ar.y += n.x + n.y + n.z;
        ar.z += n.y + n.z + n.w; ar.w += n.z + n.w + rn;
    }
    half4v ol = {(_Float16)al.x, (_Float16)al.y, (_Float16)al.z, (_Float16)al.w};
    half4v orr = {(_Float16)ar.x, (_Float16)ar.y, (_Float16)ar.z, (_Float16)ar.w};
    *(half4v*)(boxl + base + h * W + w4) = ol;
    *(half4v*)(boxr + base + h * W + w4) = orr;
}

// ---------------------------------------------------------------------------
// stage4x4_h: stage [C][W] f16 row into LDS transposed [w][c] (stride LSTRH)
// via 4x4 register transpose. Lane map t6=[cg(3b)|rw(3b)]: half4 (8B) writes
// at dword (w4+k)*20 + 2cg -> banks (20rw+2cg)%32 + pair => all 32 banks,
// 4 accesses each = conflict-free minimum. 4x fewer DS writes than scalar.
__device__ __forceinline__ void stage4x4_h(const _Float16* __restrict__ gsrc,
                                           _Float16* __restrict__ lds,
                                           int tid, int nthreads) {
    for (int j = tid; j < (W / 4) * (C / 4); j += nthreads) {   // 832
        int t6 = j & 63;
        int g  = j >> 6;              // 0..12
        int rw = t6 & 7;
        int cg = t6 >> 3;             // 0..7
        int w4 = (g * 8 + rw) * 4;    // 0..412
        int c0 = cg * 4;
        half4v r0 = *(const half4v*)(gsrc + (size_t)(c0 + 0) * HW + w4);
        half4v r1 = *(const half4v*)(gsrc + (size_t)(c0 + 1) * HW + w4);
        half4v r2 = *(const half4v*)(gsrc + (size_t)(c0 + 2) * HW + w4);
        half4v r3 = *(const half4v*)(gsrc + (size_t)(c0 + 3) * HW + w4);
#pragma unroll
        for (int k = 0; k < 4; ++k) {
            half4v col = {r0[k], r1[k], r2[k], r3[k]};
            *(half4v*)(lds + (w4 + k) * LSTRH + c0) = col;
        }
    }
}

// same but f32 source, convert-on-stage
__device__ __forceinline__ void stage4x4_cvt(const float* __restrict__ gsrc,
                                             _Float16* __restrict__ lds,
                                             int tid, int nthreads) {
    for (int j = tid; j < (W / 4) * (C / 4); j += nthreads) {
        int t6 = j & 63;
        int g  = j >> 6;
        int rw = t6 & 7;
        int cg = t6 >> 3;
        int w4 = (g * 8 + rw) * 4;
        int c0 = cg * 4;
        float4 r0 = *(const float4*)(gsrc + (size_t)(c0 + 0) * HW + w4);
        float4 r1 = *(const float4*)(gsrc + (size_t)(c0 + 1) * HW + w4);
        float4 r2 = *(const float4*)(gsrc + (size_t)(c0 + 2) * HW + w4);
        float4 r3 = *(const float4*)(gsrc + (size_t)(c0 + 3) * HW + w4);
        const float* f0 = &r0.x; const float* f1 = &r1.x;
        const float* f2 = &r2.x; const float* f3 = &r3.x;
#pragma unroll
        for (int k = 0; k < 4; ++k) {
            half4v col = {(_Float16)f0[k], (_Float16)f1[k],
                          (_Float16)f2[k], (_Float16)f3[k]};
            *(half4v*)(lds + (w4 + k) * LSTRH + c0) = col;
        }
    }
}

// dot over 32 channels: col is 16B-aligned LDS column (32 f16 = 4 b128)
__device__ __forceinline__ float dot16(const half2v* __restrict__ a,
                                       const _Float16* __restrict__ col) {
    const half8v* c8 = (const half8v*)col;
    float s = 0.f;
#pragma unroll
    for (int q = 0; q < 4; ++q) {
        half8v v = c8[q];
#pragma unroll
        for (int i = 0; i < 4; ++i) {
            half2v p = {v[2 * i], v[2 * i + 1]};
            s = FDOT2(a[4 * q + i], p, s);
        }
    }
    return s;
}

// ---------------------------------------------------------------------------
// k_e: EH[b,d,h,v] = horiz 3-tap of E, E[v] = sum_c xl[.,v+2d]*xr[.,v].
// Wave-halo shuffles; f16 LDS tile + f16 EH out; 1024 blocks, 4/CU.
__global__ __launch_bounds__(448) void k_e(const float* __restrict__ xl,
                                           const float* __restrict__ xr,
                                           _Float16* __restrict__ EH) {
    __shared__ _Float16 sXL[W * LSTRH];  // 33280 B
    int tid = threadIdx.x;
    int h = blockIdx.x;
    int b = blockIdx.y;
    int d0 = blockIdx.z * DSPL;
    int lane = tid & 63;
    int wv = tid >> 6;                // 0..6
    int v = wv * 62 + lane - 1;       // -1 .. 433
    bool vin = (v >= 0) && (v < W);
    const float* br = xr + (size_t)b * CHW + h * W;

    half2v xrv[C / 2];
#pragma unroll
    for (int c2 = 0; c2 < C / 2; ++c2) {
        float va = vin ? br[(2 * c2) * HW + v] : 0.f;
        float vb = vin ? br[(2 * c2 + 1) * HW + v] : 0.f;
        half2v x = {(_Float16)va, (_Float16)vb};
        xrv[c2] = x;
    }

    stage4x4_cvt(xl + (size_t)b * CHW + h * W, sXL, tid, 448);
    __syncthreads();

    bool wr = (lane >= 1) && (lane <= 62) && (v < W);   // v>=0 implied
    _Float16* pe = EH + (((size_t)b * D) * H + h) * W + v;
    for (int d = d0; d < d0 + DSPL; ++d) {
        int s = 2 * d;
        float e = 0.0f;
        if (vin && v + s < W) e = dot16(xrv, sXL + (v + s) * LSTRH);
        float em = __shfl_up(e, 1);
        float ep = __shfl_down(e, 1);
        float eh = em + e + ep;
        if (wr) pe[(size_t)d * HW] = (_Float16)eh;
    }
}

// ---------------------------------------------------------------------------
// k_lr: sL and sR for 12 d. One block per (b,h,dc), 448 threads, two phases
// sharing one 33KB LDS tile (4 blocks/CU). Unpaired: consecutive lanes read
// consecutive LDS columns -> b128 reads cover all 32 banks (conflict-free).
__global__ __launch_bounds__(448) void k_lr(const float* __restrict__ xm,
                                            const _Float16* __restrict__ boxl,
                                            const _Float16* __restrict__ boxr,
                                            const float* __restrict__ inl,
                                            const float* __restrict__ inr,
                                            const float* __restrict__ inm,
                                            float* __restrict__ out) {
    __shared__ _Float16 sB[W * LSTRH];   // 33280 B
    __shared__ float sIn[W];
    int tid = threadIdx.x;
    int h = blockIdx.x;
    int b = blockIdx.y;
    int d0 = blockIdx.z * DSPL;
    int w = tid;
    bool act = w < W;
    int bhw = b * HW + h * W;

    half2v fl[C / 2];
    {
        const float* pm = xm + (size_t)b * CHW + h * W;
        float im = act ? inm[bhw + w] : 0.f;
#pragma unroll
        for (int c2 = 0; c2 < C / 2; ++c2) {
            float va = act ? pm[(2 * c2) * HW + w] : 0.f;
            float vb = act ? pm[(2 * c2 + 1) * HW + w] : 0.f;
            half2v f = {(_Float16)(va * im), (_Float16)(vb * im)};
            fl[c2] = f;
        }
    }

    // ---- L phase ----
    stage4x4_h(boxl + (size_t)b * CHW + h * W, sB, tid, 448);
    for (int j = tid; j < W; j += 448) sIn[j] = inl[bhw + j];
    __syncthreads();
    if (act) {
        float* o = out + ((size_t)b * 3 + 0) * D * HW + h * W + w;
        for (int d = d0; d < d0 + DSPL; ++d) {
            float oL = 0.f;
            int v = w + d;
            if (v < W) {
                float a = dot16(fl, sB + v * LSTRH);
                oL = clip10(a * sIn[v] * ISCALE);
            }
            o[(size_t)d * HW] = oL;
        }
    }
    __syncthreads();

    // ---- R phase ----
    stage4x4_h(boxr + (size_t)b * CHW + h * W, sB, tid, 448);
    for (int j = tid; j < W; j += 448) sIn[j] = inr[bhw + j];
    __syncthreads();
    if (act) {
        float* o = out + ((size_t)b * 3 + 1) * D * HW + h * W + w;
        for (int d = d0; d < d0 + DSPL; ++d) {
            float oR = 0.f;
            int v = w - d;
            if (v >= 0) {
                float a = dot16(fl, sB + v * LSTRH);
                oR = clip10(a * sIn[v] * ISCALE);
            }
            o[(size_t)d * HW] = oR;
        }
    }
}

// ---------------------------------------------------------------------------
// k_lr2: sLR = vertical 3-tap of EH, rolling register window over h.
// Thread owns (w,d); each EH element is loaded exactly once.
__global__ __launch_bounds__(256) void k_lr2(const _Float16* __restrict__ EH,
                                             const float* __restrict__ inl,
                                             const float* __restrict__ inr,
                                             float* __restrict__ out) {
    int tid = threadIdx.x;
    int w = blockIdx.x * 256 + tid;    // grid.x = 2
    int d = blockIdx.y;                // 0..47
    int z = blockIdx.z;                // b*HC + hc
    int b = z / HC, hc = z - b * HC;
    if (w >= W) return;
    int vc = w - d;
    bool valid = (vc >= 0) && (w + d < W);
    int h0 = hc * HB;

    const _Float16* pe = EH + ((size_t)b * D + d) * HW + vc;
    const float* pl = inl + b * HW + w + d;
    const float* pr = inr + b * HW + vc;
    float* o = out + ((size_t)b * 3 + 2) * D * HW + (size_t)d * HW + w;

    float em = 0.f, e0 = 0.f;
    if (valid) {
        em = (h0 > 0) ? (float)pe[(h0 - 1) * W] : 0.f;
        e0 = (float)pe[h0 * W];
    }
#pragma unroll 4
    for (int h = h0; h < h0 + HB; ++h) {
        float r = 0.f;
        if (valid) {
            float ep = (h + 1 < H) ? (float)pe[(h + 1) * W] : 0.f;
            float e = em + e0 + ep;
            r = clip10(e * pl[h * W] * pr[h * W] * ISCALE);
            em = e0; e0 = ep;
        }
        o[h * W] = r;
    }
}

// ---------------------------------------------------------------------------
extern "C" void kernel_launch(void* const* d_in, const int* in_sizes, int n_in,
                              void* d_out, int out_size, void* d_ws, size_t ws_size,
                              hipStream_t stream) {
    const float* xl = (const float*)d_in[0];
    const float* xm = (const float*)d_in[1];
    const float* xr = (const float*)d_in[2];
    float* out = (float*)d_out;

    float* ws = (float*)d_ws;
    float* inl  = ws;                              // B*HW fp32
    float* inr  = inl + B * HW;
    float* inm  = inr + B * HW;
    float* sql  = inm + B * HW;
    float* sqr  = sql + B * HW;
    _Float16* boxl = (_Float16*)(sqr + B * HW);    // B*C*H*W f16
    _Float16* boxr = boxl + (size_t)B * CHW;
    _Float16* EH   = boxr + (size_t)B * CHW;       // B*D*H*W f16

    k_sq<<<dim3((B * HW + 255) / 256), dim3(256), 0, stream>>>(xl, xr, xm, sql, sqr, inm);
    k_norm<<<dim3((B * HW + 255) / 256), dim3(256), 0, stream>>>(sql, sqr, inl, inr);
    k_box<<<dim3((B * CHW / 4 + 255) / 256), dim3(256), 0, stream>>>(xl, xr, boxl, boxr);
    k_e<<<dim3(H, B, NDSP), dim3(448), 0, stream>>>(xl, xr, EH);
    k_lr<<<dim3(H, B, NDSP), dim3(448), 0, stream>>>(xm, boxl, boxr, inl, inr, inm, out);
    k_lr2<<<dim3(2, D, B * HC), dim3(256), 0, stream>>>(EH, inl, inr, out);
}